// Round 2
// baseline (9500.564 us; speedup 1.0000x reference)
//
#include <hip/hip_runtime.h>
#include <hip/hip_bf16.h>

#define NN 50000
#define NE 800000
#define H 128

typedef __hip_bfloat16 bf16;

// ---------------------------------------------------------------------------
// Fused edge weights: W3p[l] = ee_w2 @ W3[l]  (128x128), c3[l] = ee_b2 @ W3[l] + eb[l]
// grid 48 = 6 layers x 8 column-chunks of 16. Trivial cost.
// ---------------------------------------------------------------------------
__global__ __launch_bounds__(256) void fuse_w3_kernel(
    const float* __restrict__ ee_w2, const float* __restrict__ ee_b2,
    const float* __restrict__ mp_ew, const float* __restrict__ mp_eb,
    float* __restrict__ W3p, float* __restrict__ c3)
{
  const int l = blockIdx.x >> 3;
  const int cc = (blockIdx.x & 7) * 16;
  __shared__ float sA[H * H];     // ee_w2
  __shared__ float sB[H * 16];    // W3 column chunk
  const float* W3 = mp_ew + (size_t)l * 384 * H + 256 * H;
  for (int i = threadIdx.x; i < H * H; i += 256) sA[i] = ee_w2[i];
  for (int i = threadIdx.x; i < H * 16; i += 256) {
    int k = i >> 4, j = i & 15;
    sB[i] = W3[k * H + cc + j];
  }
  __syncthreads();
  float* out = W3p + (size_t)l * H * H;
  for (int i = threadIdx.x; i < H * 16; i += 256) {
    int r = i >> 4, j = i & 15;
    float acc = 0.f;
    #pragma unroll 8
    for (int k = 0; k < H; ++k) acc += sA[r * H + k] * sB[k * 16 + j];
    out[r * H + cc + j] = acc;
  }
  if (threadIdx.x < 16) {
    int j = threadIdx.x;
    float acc = mp_eb[l * H + cc + j];
    for (int k = 0; k < H; ++k) acc += ee_b2[k] * sB[k * 16 + j];
    c3[l * H + cc + j] = acc;
  }
}

// ---------------------------------------------------------------------------
// Node encoder: h = relu(x @ w1 + b1) @ w2 + b2   (10 -> 128 -> 128)
// 256 threads, 8 rows/iteration, weights in LDS.
// ---------------------------------------------------------------------------
__global__ __launch_bounds__(256) void node_encoder_kernel(
    const float* __restrict__ in,
    const float* __restrict__ w1, const float* __restrict__ b1,
    const float* __restrict__ w2, const float* __restrict__ b2,
    float* __restrict__ out, int nrows)
{
  __shared__ float sw1[10 * H];
  __shared__ float sw2[H * H];
  __shared__ float sb1[H];
  __shared__ float sb2[H];
  __shared__ float sin_[8][10];
  __shared__ float st[8][H];

  for (int i = threadIdx.x; i < 10 * H; i += 256) sw1[i] = w1[i];
  for (int i = threadIdx.x; i < H * H; i += 256) sw2[i] = w2[i];
  if (threadIdx.x < H) { sb1[threadIdx.x] = b1[threadIdx.x]; sb2[threadIdx.x] = b2[threadIdx.x]; }
  __syncthreads();

  const int c = threadIdx.x & 127;
  const int hf = threadIdx.x >> 7;

  for (long long r0 = (long long)blockIdx.x * 8; r0 < nrows; r0 += (long long)gridDim.x * 8) {
    if (threadIdx.x < 80) {
      int j = threadIdx.x / 10, k = threadIdx.x % 10;
      long long r = r0 + j;
      sin_[j][k] = (r < nrows) ? in[r * 10 + k] : 0.f;
    }
    __syncthreads();
    #pragma unroll
    for (int t = 0; t < 4; ++t) {
      int idx = threadIdx.x + t * 256;
      int j = idx >> 7, k = idx & 127;
      float acc = sb1[k];
      #pragma unroll
      for (int i = 0; i < 10; ++i) acc += sin_[j][i] * sw1[i * H + k];
      st[j][k] = fmaxf(acc, 0.f);
    }
    __syncthreads();
    float a0 = sb2[c], a1 = a0, a2 = a0, a3 = a0;
    #pragma unroll 4
    for (int k4 = 0; k4 < H; k4 += 4) {
      float w0 = sw2[(k4 + 0) * H + c];
      float w1v = sw2[(k4 + 1) * H + c];
      float w2v = sw2[(k4 + 2) * H + c];
      float w3v = sw2[(k4 + 3) * H + c];
      float4 s0 = *(const float4*)&st[hf * 4 + 0][k4];
      float4 s1 = *(const float4*)&st[hf * 4 + 1][k4];
      float4 s2 = *(const float4*)&st[hf * 4 + 2][k4];
      float4 s3 = *(const float4*)&st[hf * 4 + 3][k4];
      a0 += s0.x * w0 + s0.y * w1v + s0.z * w2v + s0.w * w3v;
      a1 += s1.x * w0 + s1.y * w1v + s1.z * w2v + s1.w * w3v;
      a2 += s2.x * w0 + s2.y * w1v + s2.z * w2v + s2.w * w3v;
      a3 += s3.x * w0 + s3.y * w1v + s3.z * w2v + s3.w * w3v;
    }
    float accs[4] = {a0, a1, a2, a3};
    #pragma unroll
    for (int j = 0; j < 4; ++j) {
      long long r = r0 + hf * 4 + j;
      if (r < nrows) out[r * H + c] = accs[j];
    }
    __syncthreads();
  }
}

// ---------------------------------------------------------------------------
// Per-layer node GEMMs: A = bf16(h @ W1), B = bf16(h @ W2); also zeroes agg.
// 512 threads, 16 rows/iteration.
// ---------------------------------------------------------------------------
__global__ __launch_bounds__(512) void node_AB_kernel(
    const float* __restrict__ h, const float* __restrict__ W1f, const float* __restrict__ W2f,
    bf16* __restrict__ A, bf16* __restrict__ B, float* __restrict__ agg, int nrows)
{
  __shared__ float sw1[H * H];
  __shared__ float sw2[H * H];
  __shared__ float sh[16][H];
  for (int i = threadIdx.x; i < H * H; i += 512) { sw1[i] = W1f[i]; sw2[i] = W2f[i]; }
  __syncthreads();
  const int c = threadIdx.x & 127;
  const int q = threadIdx.x >> 7;
  for (long long r0 = (long long)blockIdx.x * 16; r0 < nrows; r0 += (long long)gridDim.x * 16) {
    #pragma unroll
    for (int t = 0; t < 4; ++t) {
      int idx = threadIdx.x + t * 512;
      int j = idx >> 7, k = idx & 127;
      long long r = r0 + j;
      sh[j][k] = (r < nrows) ? h[r * H + k] : 0.f;
    }
    __syncthreads();
    float aA[4] = {0, 0, 0, 0}, aB[4] = {0, 0, 0, 0};
    #pragma unroll 2
    for (int k4 = 0; k4 < H; k4 += 4) {
      float w10 = sw1[(k4 + 0) * H + c], w11 = sw1[(k4 + 1) * H + c];
      float w12 = sw1[(k4 + 2) * H + c], w13 = sw1[(k4 + 3) * H + c];
      float w20 = sw2[(k4 + 0) * H + c], w21 = sw2[(k4 + 1) * H + c];
      float w22 = sw2[(k4 + 2) * H + c], w23 = sw2[(k4 + 3) * H + c];
      #pragma unroll
      for (int j = 0; j < 4; ++j) {
        float4 s = *(const float4*)&sh[q * 4 + j][k4];
        aA[j] += s.x * w10 + s.y * w11 + s.z * w12 + s.w * w13;
        aB[j] += s.x * w20 + s.y * w21 + s.z * w22 + s.w * w23;
      }
    }
    #pragma unroll
    for (int j = 0; j < 4; ++j) {
      long long r = r0 + q * 4 + j;
      if (r < nrows) {
        A[r * H + c] = __float2bfloat16(aA[j]);
        B[r * H + c] = __float2bfloat16(aB[j]);
        agg[r * H + c] = 0.f;
      }
    }
    __syncthreads();
  }
}

// ---------------------------------------------------------------------------
// Edge kernel: hid = relu(ea @ ew1 + eb1); msg = relu(A[src] + B[dst] + hid @ W3p + c3)
// atomicAdd into agg[dst]. 256 threads, 8 edges/iteration. ~73KB LDS.
// ---------------------------------------------------------------------------
__global__ __launch_bounds__(256) void edge_mlp_scatter(
    const float* __restrict__ ea,
    const int* __restrict__ srcI, const int* __restrict__ dstI,
    const bf16* __restrict__ A, const bf16* __restrict__ B,
    const float* __restrict__ ew1, const float* __restrict__ eb1,
    const float* __restrict__ W3p, const float* __restrict__ c3,
    float* __restrict__ agg, int nE)
{
  __shared__ float sw[H * H];      // fused W3p, 64KB
  __shared__ float sew1[7 * H];
  __shared__ float seb1[H];
  __shared__ float sc3[H];
  __shared__ float sea[8][8];
  __shared__ float shid[8][H];

  for (int i = threadIdx.x; i < H * H; i += 256) sw[i] = W3p[i];
  for (int i = threadIdx.x; i < 7 * H; i += 256) sew1[i] = ew1[i];
  if (threadIdx.x < H) { seb1[threadIdx.x] = eb1[threadIdx.x]; sc3[threadIdx.x] = c3[threadIdx.x]; }
  __syncthreads();
  const int c = threadIdx.x & 127;
  const int hf = threadIdx.x >> 7;
  for (long long e0 = (long long)blockIdx.x * 8; e0 < nE; e0 += (long long)gridDim.x * 8) {
    if (threadIdx.x < 56) {
      long long flat = e0 * 7 + threadIdx.x;
      int j = threadIdx.x / 7, k = threadIdx.x % 7;
      sea[j][k] = (flat < (long long)nE * 7) ? ea[flat] : 0.f;
    }
    __syncthreads();
    // hidden layer: 8 x 128 outputs, 7-term dots
    #pragma unroll
    for (int t = 0; t < 4; ++t) {
      int idx = threadIdx.x + t * 256;
      int j = idx >> 7, k = idx & 127;
      float acc = seb1[k];
      #pragma unroll
      for (int i = 0; i < 7; ++i) acc += sea[j][i] * sew1[i * H + k];
      shid[j][k] = fmaxf(acc, 0.f);
    }
    __syncthreads();
    // main 128x128 GEMM from hidden
    float a0 = sc3[c], a1 = a0, a2 = a0, a3 = a0;
    #pragma unroll 4
    for (int k4 = 0; k4 < H; k4 += 4) {
      float w0 = sw[(k4 + 0) * H + c];
      float w1v = sw[(k4 + 1) * H + c];
      float w2v = sw[(k4 + 2) * H + c];
      float w3v = sw[(k4 + 3) * H + c];
      float4 s0 = *(const float4*)&shid[hf * 4 + 0][k4];
      float4 s1 = *(const float4*)&shid[hf * 4 + 1][k4];
      float4 s2 = *(const float4*)&shid[hf * 4 + 2][k4];
      float4 s3 = *(const float4*)&shid[hf * 4 + 3][k4];
      a0 += s0.x * w0 + s0.y * w1v + s0.z * w2v + s0.w * w3v;
      a1 += s1.x * w0 + s1.y * w1v + s1.z * w2v + s1.w * w3v;
      a2 += s2.x * w0 + s2.y * w1v + s2.z * w2v + s2.w * w3v;
      a3 += s3.x * w0 + s3.y * w1v + s3.z * w2v + s3.w * w3v;
    }
    float accs[4] = {a0, a1, a2, a3};
    #pragma unroll
    for (int j = 0; j < 4; ++j) {
      long long eid = e0 + hf * 4 + j;
      if (eid < nE) {
        int s = srcI[eid], d = dstI[eid];
        float m = accs[j] + __bfloat162float(A[(size_t)s * H + c])
                          + __bfloat162float(B[(size_t)d * H + c]);
        atomicAdd(&agg[(size_t)d * H + c], fmaxf(m, 0.f));
      }
    }
    __syncthreads();
  }
}

// ---------------------------------------------------------------------------
// Node update: h = h + relu(h @ Wn1 + agg @ Wn2 + nb). 512 threads, 16 rows/iter.
// ---------------------------------------------------------------------------
__global__ __launch_bounds__(512) void node_update_kernel(
    float* __restrict__ h, const float* __restrict__ agg,
    const float* __restrict__ Wn1, const float* __restrict__ Wn2,
    const float* __restrict__ nb, int nrows)
{
  __shared__ float sw1[H * H];
  __shared__ float sw2[H * H];
  __shared__ float snb[H];
  __shared__ float sh[16][H];
  __shared__ float sa[16][H];
  for (int i = threadIdx.x; i < H * H; i += 512) { sw1[i] = Wn1[i]; sw2[i] = Wn2[i]; }
  if (threadIdx.x < H) snb[threadIdx.x] = nb[threadIdx.x];
  __syncthreads();
  const int c = threadIdx.x & 127;
  const int q = threadIdx.x >> 7;
  for (long long r0 = (long long)blockIdx.x * 16; r0 < nrows; r0 += (long long)gridDim.x * 16) {
    #pragma unroll
    for (int t = 0; t < 4; ++t) {
      int idx = threadIdx.x + t * 512;
      int j = idx >> 7, k = idx & 127;
      long long r = r0 + j;
      sh[j][k] = (r < nrows) ? h[r * H + k] : 0.f;
      sa[j][k] = (r < nrows) ? agg[r * H + k] : 0.f;
    }
    __syncthreads();
    float acc[4];
    #pragma unroll
    for (int j = 0; j < 4; ++j) acc[j] = snb[c];
    #pragma unroll 2
    for (int k4 = 0; k4 < H; k4 += 4) {
      float w10 = sw1[(k4 + 0) * H + c], w11 = sw1[(k4 + 1) * H + c];
      float w12 = sw1[(k4 + 2) * H + c], w13 = sw1[(k4 + 3) * H + c];
      float w20 = sw2[(k4 + 0) * H + c], w21 = sw2[(k4 + 1) * H + c];
      float w22 = sw2[(k4 + 2) * H + c], w23 = sw2[(k4 + 3) * H + c];
      #pragma unroll
      for (int j = 0; j < 4; ++j) {
        float4 s = *(const float4*)&sh[q * 4 + j][k4];
        float4 g = *(const float4*)&sa[q * 4 + j][k4];
        acc[j] += s.x * w10 + s.y * w11 + s.z * w12 + s.w * w13;
        acc[j] += g.x * w20 + g.y * w21 + g.z * w22 + g.w * w23;
      }
    }
    #pragma unroll
    for (int j = 0; j < 4; ++j) {
      long long r = r0 + q * 4 + j;
      if (r < nrows) h[r * H + c] = sh[q * 4 + j][c] + fmaxf(acc[j], 0.f);
    }
    __syncthreads();
  }
}

// ---------------------------------------------------------------------------
// Decoder: pred = relu(relu(h@w1+b1)@w2+b2)@w3+b3, then BC mask. 512 thr, 16 rows.
// ---------------------------------------------------------------------------
__global__ __launch_bounds__(512) void decoder_kernel(
    const float* __restrict__ h,
    const float* __restrict__ w1, const float* __restrict__ b1,
    const float* __restrict__ w2, const float* __restrict__ b2,
    const float* __restrict__ w3, const float* __restrict__ b3,
    const float* __restrict__ bcd, const float* __restrict__ bcr,
    float* __restrict__ out, int nrows)
{
  __shared__ float sw1[H * H];
  __shared__ float sw2[H * 64];
  __shared__ float sw3[64 * 3];
  __shared__ float sb1[H], sb2[64], sb3[3];
  __shared__ float sh[16][H], st1[16][H], st2[16][64];
  for (int i = threadIdx.x; i < H * H; i += 512) sw1[i] = w1[i];
  for (int i = threadIdx.x; i < H * 64; i += 512) sw2[i] = w2[i];
  if (threadIdx.x < 64 * 3) sw3[threadIdx.x] = w3[threadIdx.x];
  if (threadIdx.x < H) sb1[threadIdx.x] = b1[threadIdx.x];
  if (threadIdx.x < 64) sb2[threadIdx.x] = b2[threadIdx.x];
  if (threadIdx.x < 3) sb3[threadIdx.x] = b3[threadIdx.x];
  __syncthreads();
  for (long long r0 = (long long)blockIdx.x * 16; r0 < nrows; r0 += (long long)gridDim.x * 16) {
    #pragma unroll
    for (int t = 0; t < 4; ++t) {
      int idx = threadIdx.x + t * 512;
      int j = idx >> 7, k = idx & 127;
      long long r = r0 + j;
      sh[j][k] = (r < nrows) ? h[r * H + k] : 0.f;
    }
    __syncthreads();
    #pragma unroll
    for (int t = 0; t < 4; ++t) {
      int idx = threadIdx.x + t * 512;
      int j = idx >> 7, k = idx & 127;
      float acc = sb1[k];
      #pragma unroll 8
      for (int i = 0; i < H; ++i) acc += sh[j][i] * sw1[i * H + k];
      st1[j][k] = fmaxf(acc, 0.f);
    }
    __syncthreads();
    #pragma unroll
    for (int t = 0; t < 2; ++t) {
      int idx = threadIdx.x + t * 512;
      int j = idx >> 6, k = idx & 63;
      float acc = sb2[k];
      #pragma unroll 8
      for (int i = 0; i < H; ++i) acc += st1[j][i] * sw2[i * 64 + k];
      st2[j][k] = fmaxf(acc, 0.f);
    }
    __syncthreads();
    if (threadIdx.x < 48) {
      int j = threadIdx.x / 3, o = threadIdx.x % 3;
      float acc = sb3[o];
      #pragma unroll 8
      for (int i = 0; i < 64; ++i) acc += st2[j][i] * sw3[i * 3 + o];
      long long r = r0 + j;
      if (r < nrows) {
        float m = (o < 2) ? (1.f - bcd[r]) : (1.f - bcr[r]);
        out[r * 3 + o] = acc * m;
      }
    }
    __syncthreads();
  }
}

extern "C" void kernel_launch(void* const* d_in, const int* in_sizes, int n_in,
                              void* d_out, int out_size, void* d_ws, size_t ws_size,
                              hipStream_t stream) {
  const float* x     = (const float*)d_in[0];
  const float* ea    = (const float*)d_in[1];
  const int*   eidx  = (const int*)d_in[2];
  const float* bcd   = (const float*)d_in[3];
  const float* bcr   = (const float*)d_in[4];
  const float* ne_w1 = (const float*)d_in[5];
  const float* ne_b1 = (const float*)d_in[6];
  const float* ne_w2 = (const float*)d_in[7];
  const float* ne_b2 = (const float*)d_in[8];
  const float* ee_w1 = (const float*)d_in[9];
  const float* ee_b1 = (const float*)d_in[10];
  const float* ee_w2 = (const float*)d_in[11];
  const float* ee_b2 = (const float*)d_in[12];
  const float* mp_ew = (const float*)d_in[13];
  const float* mp_eb = (const float*)d_in[14];
  const float* mp_nw = (const float*)d_in[15];
  const float* mp_nb = (const float*)d_in[16];
  const float* d_w1  = (const float*)d_in[17];
  const float* d_b1  = (const float*)d_in[18];
  const float* d_w2  = (const float*)d_in[19];
  const float* d_b2  = (const float*)d_in[20];
  const float* d_w3  = (const float*)d_in[21];
  const float* d_b3  = (const float*)d_in[22];

  const int* srcI = eidx;           // edge_index[0]
  const int* dstI = eidx + NE;      // edge_index[1]

  // workspace layout (~77.2 MB total):
  // h (f32 25.6MB) | agg (f32 25.6MB) | A (bf16 12.8MB) | B (bf16 12.8MB) | W3p (384KB) | c3 (3KB)
  char* wsp = (char*)d_ws;
  float* h   = (float*)wsp; wsp += (size_t)NN * H * 4;
  float* agg = (float*)wsp; wsp += (size_t)NN * H * 4;
  bf16*  A   = (bf16*)wsp;  wsp += (size_t)NN * H * 2;
  bf16*  B   = (bf16*)wsp;  wsp += (size_t)NN * H * 2;
  float* W3p = (float*)wsp; wsp += (size_t)6 * H * H * 4;
  float* c3  = (float*)wsp; wsp += (size_t)6 * H * 4;

  fuse_w3_kernel<<<48, 256, 0, stream>>>(ee_w2, ee_b2, mp_ew, mp_eb, W3p, c3);
  node_encoder_kernel<<<2048, 256, 0, stream>>>(x, ne_w1, ne_b1, ne_w2, ne_b2, h, NN);

  for (int l = 0; l < 6; ++l) {
    const float* W  = mp_ew + (size_t)l * 384 * H;
    const float* W1 = W;                // rows   0..127: h[src]
    const float* W2 = W + 128 * H;      // rows 128..255: h[dst]
    const float* Wn = mp_nw + (size_t)l * 256 * H;
    const float* nb = mp_nb + l * H;

    node_AB_kernel<<<1024, 512, 0, stream>>>(h, W1, W2, A, B, agg, NN);
    edge_mlp_scatter<<<4096, 256, 0, stream>>>(ea, srcI, dstI, A, B, ee_w1, ee_b1,
                                               W3p + (size_t)l * H * H, c3 + l * H, agg, NE);
    node_update_kernel<<<1024, 512, 0, stream>>>(h, agg, Wn, Wn + 128 * H, nb, NN);
  }

  decoder_kernel<<<1024, 512, 0, stream>>>(h, d_w1, d_b1, d_w2, d_b2, d_w3, d_b3,
                                           bcd, bcr, (float*)d_out, NN);
}

// Round 3
// 4103.496 us; speedup vs baseline: 2.3152x; 2.3152x over previous
//
#include <hip/hip_runtime.h>
#include <hip/hip_bf16.h>

#define NN 50000
#define NE 800000
#define H 128

typedef __hip_bfloat16 bf16;
typedef __attribute__((ext_vector_type(8))) short short8v;
typedef __attribute__((ext_vector_type(4))) float f32x4;

static __device__ __forceinline__ unsigned short f2bf_bits(float x) {
  union { __hip_bfloat16 b; unsigned short u; } cv;
  cv.b = __float2bfloat16(x);
  return cv.u;
}

// ---------------------------------------------------------------------------
// Fused edge weights: W3p[l] = ee_w2 @ W3[l]  (128x128 f32), c3[l] = ee_b2 @ W3[l] + eb[l]
// grid 48 = 6 layers x 8 column-chunks of 16.
// ---------------------------------------------------------------------------
__global__ __launch_bounds__(256) void fuse_w3_kernel(
    const float* __restrict__ ee_w2, const float* __restrict__ ee_b2,
    const float* __restrict__ mp_ew, const float* __restrict__ mp_eb,
    float* __restrict__ W3p, float* __restrict__ c3)
{
  const int l = blockIdx.x >> 3;
  const int cc = (blockIdx.x & 7) * 16;
  __shared__ float sA[H * H];
  __shared__ float sB[H * 16];
  const float* W3 = mp_ew + (size_t)l * 384 * H + 256 * H;
  for (int i = threadIdx.x; i < H * H; i += 256) sA[i] = ee_w2[i];
  for (int i = threadIdx.x; i < H * 16; i += 256) {
    int k = i >> 4, j = i & 15;
    sB[i] = W3[k * H + cc + j];
  }
  __syncthreads();
  float* out = W3p + (size_t)l * H * H;
  for (int i = threadIdx.x; i < H * 16; i += 256) {
    int r = i >> 4, j = i & 15;
    float acc = 0.f;
    #pragma unroll 8
    for (int k = 0; k < H; ++k) acc += sA[r * H + k] * sB[k * 16 + j];
    out[r * H + cc + j] = acc;
  }
  if (threadIdx.x < 16) {
    int j = threadIdx.x;
    float acc = mp_eb[l * H + cc + j];
    for (int k = 0; k < H; ++k) acc += ee_b2[k] * sB[k * 16 + j];
    c3[l * H + cc + j] = acc;
  }
}

// ---------------------------------------------------------------------------
// Repack W3p (f32 row-major [k][col]) into bf16 MFMA B-fragment order:
// W3b[l][ng*256 + kk*64 + lane][j] = W3p[l][kk*32+(lane>>4)*8+j][ng*16+(lane&15)]
// ---------------------------------------------------------------------------
__global__ __launch_bounds__(256) void repack_w3_kernel(
    const float* __restrict__ W3p, bf16* __restrict__ W3b)
{
  const int l = blockIdx.x;
  const float* src = W3p + (size_t)l * H * H;
  bf16* dst = W3b + (size_t)l * H * H;
  for (int idx = threadIdx.x; idx < 8 * 4 * 64; idx += 256) {
    int ng = idx >> 8;
    int kk = (idx >> 6) & 3;
    int ln = idx & 63;
    #pragma unroll
    for (int j = 0; j < 8; ++j) {
      int k = kk * 32 + (ln >> 4) * 8 + j;
      int col = ng * 16 + (ln & 15);
      dst[(size_t)idx * 8 + j] = __float2bfloat16(src[k * H + col]);
    }
  }
}

// ---------------------------------------------------------------------------
// Node encoder: h = relu(x @ w1 + b1) @ w2 + b2   (10 -> 128 -> 128)
// ---------------------------------------------------------------------------
__global__ __launch_bounds__(256) void node_encoder_kernel(
    const float* __restrict__ in,
    const float* __restrict__ w1, const float* __restrict__ b1,
    const float* __restrict__ w2, const float* __restrict__ b2,
    float* __restrict__ out, int nrows)
{
  __shared__ float sw1[10 * H];
  __shared__ float sw2[H * H];
  __shared__ float sb1[H];
  __shared__ float sb2[H];
  __shared__ float sin_[8][10];
  __shared__ float st[8][H];

  for (int i = threadIdx.x; i < 10 * H; i += 256) sw1[i] = w1[i];
  for (int i = threadIdx.x; i < H * H; i += 256) sw2[i] = w2[i];
  if (threadIdx.x < H) { sb1[threadIdx.x] = b1[threadIdx.x]; sb2[threadIdx.x] = b2[threadIdx.x]; }
  __syncthreads();

  const int c = threadIdx.x & 127;
  const int hf = threadIdx.x >> 7;

  for (long long r0 = (long long)blockIdx.x * 8; r0 < nrows; r0 += (long long)gridDim.x * 8) {
    if (threadIdx.x < 80) {
      int j = threadIdx.x / 10, k = threadIdx.x % 10;
      long long r = r0 + j;
      sin_[j][k] = (r < nrows) ? in[r * 10 + k] : 0.f;
    }
    __syncthreads();
    #pragma unroll
    for (int t = 0; t < 4; ++t) {
      int idx = threadIdx.x + t * 256;
      int j = idx >> 7, k = idx & 127;
      float acc = sb1[k];
      #pragma unroll
      for (int i = 0; i < 10; ++i) acc += sin_[j][i] * sw1[i * H + k];
      st[j][k] = fmaxf(acc, 0.f);
    }
    __syncthreads();
    float a0 = sb2[c], a1 = a0, a2 = a0, a3 = a0;
    #pragma unroll 4
    for (int k4 = 0; k4 < H; k4 += 4) {
      float w0 = sw2[(k4 + 0) * H + c];
      float w1v = sw2[(k4 + 1) * H + c];
      float w2v = sw2[(k4 + 2) * H + c];
      float w3v = sw2[(k4 + 3) * H + c];
      float4 s0 = *(const float4*)&st[hf * 4 + 0][k4];
      float4 s1 = *(const float4*)&st[hf * 4 + 1][k4];
      float4 s2 = *(const float4*)&st[hf * 4 + 2][k4];
      float4 s3 = *(const float4*)&st[hf * 4 + 3][k4];
      a0 += s0.x * w0 + s0.y * w1v + s0.z * w2v + s0.w * w3v;
      a1 += s1.x * w0 + s1.y * w1v + s1.z * w2v + s1.w * w3v;
      a2 += s2.x * w0 + s2.y * w1v + s2.z * w2v + s2.w * w3v;
      a3 += s3.x * w0 + s3.y * w1v + s3.z * w2v + s3.w * w3v;
    }
    float accs[4] = {a0, a1, a2, a3};
    #pragma unroll
    for (int j = 0; j < 4; ++j) {
      long long r = r0 + hf * 4 + j;
      if (r < nrows) out[r * H + c] = accs[j];
    }
    __syncthreads();
  }
}

// ---------------------------------------------------------------------------
// Per-layer node GEMMs: A = bf16(h @ W1), B = bf16(h @ W2); also zeroes agg.
// ---------------------------------------------------------------------------
__global__ __launch_bounds__(512) void node_AB_kernel(
    const float* __restrict__ h, const float* __restrict__ W1f, const float* __restrict__ W2f,
    bf16* __restrict__ A, bf16* __restrict__ B, float* __restrict__ agg, int nrows)
{
  __shared__ float sw1[H * H];
  __shared__ float sw2[H * H];
  __shared__ float sh[16][H];
  for (int i = threadIdx.x; i < H * H; i += 512) { sw1[i] = W1f[i]; sw2[i] = W2f[i]; }
  __syncthreads();
  const int c = threadIdx.x & 127;
  const int q = threadIdx.x >> 7;
  for (long long r0 = (long long)blockIdx.x * 16; r0 < nrows; r0 += (long long)gridDim.x * 16) {
    #pragma unroll
    for (int t = 0; t < 4; ++t) {
      int idx = threadIdx.x + t * 512;
      int j = idx >> 7, k = idx & 127;
      long long r = r0 + j;
      sh[j][k] = (r < nrows) ? h[r * H + k] : 0.f;
    }
    __syncthreads();
    float aA[4] = {0, 0, 0, 0}, aB[4] = {0, 0, 0, 0};
    #pragma unroll 2
    for (int k4 = 0; k4 < H; k4 += 4) {
      float w10 = sw1[(k4 + 0) * H + c], w11 = sw1[(k4 + 1) * H + c];
      float w12 = sw1[(k4 + 2) * H + c], w13 = sw1[(k4 + 3) * H + c];
      float w20 = sw2[(k4 + 0) * H + c], w21 = sw2[(k4 + 1) * H + c];
      float w22 = sw2[(k4 + 2) * H + c], w23 = sw2[(k4 + 3) * H + c];
      #pragma unroll
      for (int j = 0; j < 4; ++j) {
        float4 s = *(const float4*)&sh[q * 4 + j][k4];
        aA[j] += s.x * w10 + s.y * w11 + s.z * w12 + s.w * w13;
        aB[j] += s.x * w20 + s.y * w21 + s.z * w22 + s.w * w23;
      }
    }
    #pragma unroll
    for (int j = 0; j < 4; ++j) {
      long long r = r0 + q * 4 + j;
      if (r < nrows) {
        A[r * H + c] = __float2bfloat16(aA[j]);
        B[r * H + c] = __float2bfloat16(aB[j]);
        agg[r * H + c] = 0.f;
      }
    }
    __syncthreads();
  }
}

// ---------------------------------------------------------------------------
// Edge kernel (MFMA): per 32-edge tile:
//   hid = relu(ea @ ew1 + eb1)  -> bf16, XOR-swizzled LDS
//   msg32 = hid @ W3b (mfma_f32_16x16x32_bf16, 4 waves x 32-col slices)
//   val = relu(msg32 + c3 + A[src] + B[dst]); atomicAdd agg[dst]
// NE % 32 == 0 (800000/32 = 25000 tiles), so no tail guards.
// ---------------------------------------------------------------------------
__global__ __launch_bounds__(256) void edge_mfma_scatter(
    const float* __restrict__ ea,
    const int* __restrict__ srcI, const int* __restrict__ dstI,
    const bf16* __restrict__ A, const bf16* __restrict__ B,
    const float* __restrict__ ew1, const float* __restrict__ eb1,
    const bf16* __restrict__ W3b, const float* __restrict__ c3,
    float* __restrict__ agg, int nE)
{
  __shared__ float sew1[7 * H];     // 3.5 KB
  __shared__ float seb1[H];
  __shared__ float sea[32][8];      // ea rows (7 used, pad 8)
  __shared__ int   sidx[32];
  __shared__ int   didx[32];
  __shared__ unsigned int shid[32 * 64];  // bf16x2 words, swizzled: byte ^= (row&7)<<4

  for (int i = threadIdx.x; i < 7 * H; i += 256) sew1[i] = ew1[i];
  if (threadIdx.x < H) seb1[threadIdx.x] = eb1[threadIdx.x];

  const int t = threadIdx.x;
  const int lane = t & 63;
  const int wid = t >> 6;
  const int colbase = wid * 32;

  // per-wave B fragments (resident in VGPRs) + c3 values
  short8v bfrag[2][4];
  float c3v[2];
  #pragma unroll
  for (int n = 0; n < 2; ++n) {
    c3v[n] = c3[colbase + n * 16 + (lane & 15)];
    int ng = (colbase >> 4) + n;
    #pragma unroll
    for (int kk = 0; kk < 4; ++kk) {
      const bf16* p = W3b + ((size_t)(ng * 4 + kk) * 64 + lane) * 8;
      bfrag[n][kk] = *(const short8v*)p;
    }
  }
  __syncthreads();

  for (long long e0 = (long long)blockIdx.x * 32; e0 < nE; e0 += (long long)gridDim.x * 32) {
    // ---- stage ea rows + src/dst indices ----
    if (t < 224) sea[t / 7][t % 7] = ea[e0 * 7 + t];
    else         sidx[t - 224] = srcI[e0 + (t - 224)];
    if (t < 32)  didx[t] = dstI[e0 + t];
    __syncthreads();

    // ---- hidden layer: each thread -> edge e = t>>3, 8 bf16x2 words ----
    {
      const int e = t >> 3;
      float r0 = sea[e][0], r1 = sea[e][1], r2 = sea[e][2], r3 = sea[e][3];
      float r4 = sea[e][4], r5 = sea[e][5], r6 = sea[e][6];
      #pragma unroll
      for (int p = 0; p < 8; ++p) {
        int k2 = (t & 7) + 8 * p;
        int k = k2 * 2;
        float a0 = seb1[k], a1 = seb1[k + 1];
        a0 += r0 * sew1[0 * H + k] + r1 * sew1[1 * H + k] + r2 * sew1[2 * H + k]
            + r3 * sew1[3 * H + k] + r4 * sew1[4 * H + k] + r5 * sew1[5 * H + k]
            + r6 * sew1[6 * H + k];
        a1 += r0 * sew1[0 * H + k + 1] + r1 * sew1[1 * H + k + 1] + r2 * sew1[2 * H + k + 1]
            + r3 * sew1[3 * H + k + 1] + r4 * sew1[4 * H + k + 1] + r5 * sew1[5 * H + k + 1]
            + r6 * sew1[6 * H + k + 1];
        a0 = fmaxf(a0, 0.f); a1 = fmaxf(a1, 0.f);
        unsigned int w = (unsigned int)f2bf_bits(a0) | ((unsigned int)f2bf_bits(a1) << 16);
        int off = (e * 256 + k2 * 4) ^ ((e & 7) << 4);
        shid[off >> 2] = w;
      }
    }
    __syncthreads();

    // ---- A fragments + MFMA ----
    f32x4 acc[2][2];
    const f32x4 z = {0.f, 0.f, 0.f, 0.f};
    acc[0][0] = z; acc[0][1] = z; acc[1][0] = z; acc[1][1] = z;
    #pragma unroll
    for (int m = 0; m < 2; ++m) {
      #pragma unroll
      for (int kk = 0; kk < 4; ++kk) {
        int row = m * 16 + (lane & 15);
        int off = (row * 256 + kk * 64 + (lane >> 4) * 16) ^ ((row & 7) << 4);
        short8v afrag = *(const short8v*)((const char*)shid + off);
        acc[m][0] = __builtin_amdgcn_mfma_f32_16x16x32_bf16(afrag, bfrag[0][kk], acc[m][0], 0, 0, 0);
        acc[m][1] = __builtin_amdgcn_mfma_f32_16x16x32_bf16(afrag, bfrag[1][kk], acc[m][1], 0, 0, 0);
      }
    }

    // ---- epilogue: + c3 + A[src] + B[dst], relu, atomic scatter ----
    #pragma unroll
    for (int m = 0; m < 2; ++m) {
      #pragma unroll
      for (int r = 0; r < 4; ++r) {
        int el = m * 16 + (lane >> 4) * 4 + r;
        int s = sidx[el];
        int d = didx[el];
        #pragma unroll
        for (int n = 0; n < 2; ++n) {
          int col = colbase + n * 16 + (lane & 15);
          float v = acc[m][n][r] + c3v[n]
                  + __bfloat162float(A[(size_t)s * H + col])
                  + __bfloat162float(B[(size_t)d * H + col]);
          atomicAdd(&agg[(size_t)d * H + col], fmaxf(v, 0.f));
        }
      }
    }
    __syncthreads();
  }
}

// ---------------------------------------------------------------------------
// Node update: h = h + relu(h @ Wn1 + agg @ Wn2 + nb). 512 threads, 16 rows/iter.
// ---------------------------------------------------------------------------
__global__ __launch_bounds__(512) void node_update_kernel(
    float* __restrict__ h, const float* __restrict__ agg,
    const float* __restrict__ Wn1, const float* __restrict__ Wn2,
    const float* __restrict__ nb, int nrows)
{
  __shared__ float sw1[H * H];
  __shared__ float sw2[H * H];
  __shared__ float snb[H];
  __shared__ float sh[16][H];
  __shared__ float sa[16][H];
  for (int i = threadIdx.x; i < H * H; i += 512) { sw1[i] = Wn1[i]; sw2[i] = Wn2[i]; }
  if (threadIdx.x < H) snb[threadIdx.x] = nb[threadIdx.x];
  __syncthreads();
  const int c = threadIdx.x & 127;
  const int q = threadIdx.x >> 7;
  for (long long r0 = (long long)blockIdx.x * 16; r0 < nrows; r0 += (long long)gridDim.x * 16) {
    #pragma unroll
    for (int t = 0; t < 4; ++t) {
      int idx = threadIdx.x + t * 512;
      int j = idx >> 7, k = idx & 127;
      long long r = r0 + j;
      sh[j][k] = (r < nrows) ? h[r * H + k] : 0.f;
      sa[j][k] = (r < nrows) ? agg[r * H + k] : 0.f;
    }
    __syncthreads();
    float acc[4];
    #pragma unroll
    for (int j = 0; j < 4; ++j) acc[j] = snb[c];
    #pragma unroll 2
    for (int k4 = 0; k4 < H; k4 += 4) {
      float w10 = sw1[(k4 + 0) * H + c], w11 = sw1[(k4 + 1) * H + c];
      float w12 = sw1[(k4 + 2) * H + c], w13 = sw1[(k4 + 3) * H + c];
      float w20 = sw2[(k4 + 0) * H + c], w21 = sw2[(k4 + 1) * H + c];
      float w22 = sw2[(k4 + 2) * H + c], w23 = sw2[(k4 + 3) * H + c];
      #pragma unroll
      for (int j = 0; j < 4; ++j) {
        float4 s = *(const float4*)&sh[q * 4 + j][k4];
        float4 g = *(const float4*)&sa[q * 4 + j][k4];
        acc[j] += s.x * w10 + s.y * w11 + s.z * w12 + s.w * w13;
        acc[j] += g.x * w20 + g.y * w21 + g.z * w22 + g.w * w23;
      }
    }
    #pragma unroll
    for (int j = 0; j < 4; ++j) {
      long long r = r0 + q * 4 + j;
      if (r < nrows) h[r * H + c] = sh[q * 4 + j][c] + fmaxf(acc[j], 0.f);
    }
    __syncthreads();
  }
}

// ---------------------------------------------------------------------------
// Decoder: pred = relu(relu(h@w1+b1)@w2+b2)@w3+b3, then BC mask.
// ---------------------------------------------------------------------------
__global__ __launch_bounds__(512) void decoder_kernel(
    const float* __restrict__ h,
    const float* __restrict__ w1, const float* __restrict__ b1,
    const float* __restrict__ w2, const float* __restrict__ b2,
    const float* __restrict__ w3, const float* __restrict__ b3,
    const float* __restrict__ bcd, const float* __restrict__ bcr,
    float* __restrict__ out, int nrows)
{
  __shared__ float sw1[H * H];
  __shared__ float sw2[H * 64];
  __shared__ float sw3[64 * 3];
  __shared__ float sb1[H], sb2[64], sb3[3];
  __shared__ float sh[16][H], st1[16][H], st2[16][64];
  for (int i = threadIdx.x; i < H * H; i += 512) sw1[i] = w1[i];
  for (int i = threadIdx.x; i < H * 64; i += 512) sw2[i] = w2[i];
  if (threadIdx.x < 64 * 3) sw3[threadIdx.x] = w3[threadIdx.x];
  if (threadIdx.x < H) sb1[threadIdx.x] = b1[threadIdx.x];
  if (threadIdx.x < 64) sb2[threadIdx.x] = b2[threadIdx.x];
  if (threadIdx.x < 3) sb3[threadIdx.x] = b3[threadIdx.x];
  __syncthreads();
  for (long long r0 = (long long)blockIdx.x * 16; r0 < nrows; r0 += (long long)gridDim.x * 16) {
    #pragma unroll
    for (int t = 0; t < 4; ++t) {
      int idx = threadIdx.x + t * 512;
      int j = idx >> 7, k = idx & 127;
      long long r = r0 + j;
      sh[j][k] = (r < nrows) ? h[r * H + k] : 0.f;
    }
    __syncthreads();
    #pragma unroll
    for (int t = 0; t < 4; ++t) {
      int idx = threadIdx.x + t * 512;
      int j = idx >> 7, k = idx & 127;
      float acc = sb1[k];
      #pragma unroll 8
      for (int i = 0; i < H; ++i) acc += sh[j][i] * sw1[i * H + k];
      st1[j][k] = fmaxf(acc, 0.f);
    }
    __syncthreads();
    #pragma unroll
    for (int t = 0; t < 2; ++t) {
      int idx = threadIdx.x + t * 512;
      int j = idx >> 6, k = idx & 63;
      float acc = sb2[k];
      #pragma unroll 8
      for (int i = 0; i < H; ++i) acc += st1[j][i] * sw2[i * 64 + k];
      st2[j][k] = fmaxf(acc, 0.f);
    }
    __syncthreads();
    if (threadIdx.x < 48) {
      int j = threadIdx.x / 3, o = threadIdx.x % 3;
      float acc = sb3[o];
      #pragma unroll 8
      for (int i = 0; i < 64; ++i) acc += st2[j][i] * sw3[i * 3 + o];
      long long r = r0 + j;
      if (r < nrows) {
        float m = (o < 2) ? (1.f - bcd[r]) : (1.f - bcr[r]);
        out[r * 3 + o] = acc * m;
      }
    }
    __syncthreads();
  }
}

extern "C" void kernel_launch(void* const* d_in, const int* in_sizes, int n_in,
                              void* d_out, int out_size, void* d_ws, size_t ws_size,
                              hipStream_t stream) {
  const float* x     = (const float*)d_in[0];
  const float* ea    = (const float*)d_in[1];
  const int*   eidx  = (const int*)d_in[2];
  const float* bcd   = (const float*)d_in[3];
  const float* bcr   = (const float*)d_in[4];
  const float* ne_w1 = (const float*)d_in[5];
  const float* ne_b1 = (const float*)d_in[6];
  const float* ne_w2 = (const float*)d_in[7];
  const float* ne_b2 = (const float*)d_in[8];
  const float* ee_w1 = (const float*)d_in[9];
  const float* ee_b1 = (const float*)d_in[10];
  const float* ee_w2 = (const float*)d_in[11];
  const float* ee_b2 = (const float*)d_in[12];
  const float* mp_ew = (const float*)d_in[13];
  const float* mp_eb = (const float*)d_in[14];
  const float* mp_nw = (const float*)d_in[15];
  const float* mp_nb = (const float*)d_in[16];
  const float* d_w1  = (const float*)d_in[17];
  const float* d_b1  = (const float*)d_in[18];
  const float* d_w2  = (const float*)d_in[19];
  const float* d_b2  = (const float*)d_in[20];
  const float* d_w3  = (const float*)d_in[21];
  const float* d_b3  = (const float*)d_in[22];

  const int* srcI = eidx;           // edge_index[0]
  const int* dstI = eidx + NE;      // edge_index[1]

  // workspace (~77.4 MB):
  // h f32 | agg f32 | A bf16 | B bf16 | W3p f32 | W3b bf16 | c3 f32
  char* wsp = (char*)d_ws;
  float* h   = (float*)wsp; wsp += (size_t)NN * H * 4;
  float* agg = (float*)wsp; wsp += (size_t)NN * H * 4;
  bf16*  A   = (bf16*)wsp;  wsp += (size_t)NN * H * 2;
  bf16*  B   = (bf16*)wsp;  wsp += (size_t)NN * H * 2;
  float* W3p = (float*)wsp; wsp += (size_t)6 * H * H * 4;
  bf16*  W3b = (bf16*)wsp;  wsp += (size_t)6 * H * H * 2;
  float* c3  = (float*)wsp; wsp += (size_t)6 * H * 4;

  fuse_w3_kernel<<<48, 256, 0, stream>>>(ee_w2, ee_b2, mp_ew, mp_eb, W3p, c3);
  repack_w3_kernel<<<6, 256, 0, stream>>>(W3p, W3b);
  node_encoder_kernel<<<2048, 256, 0, stream>>>(x, ne_w1, ne_b1, ne_w2, ne_b2, h, NN);

  for (int l = 0; l < 6; ++l) {
    const float* W  = mp_ew + (size_t)l * 384 * H;
    const float* W1 = W;                // rows   0..127: h[src]
    const float* W2 = W + 128 * H;      // rows 128..255: h[dst]
    const float* Wn = mp_nw + (size_t)l * 256 * H;
    const float* nb = mp_nb + l * H;

    node_AB_kernel<<<1024, 512, 0, stream>>>(h, W1, W2, A, B, agg, NN);
    edge_mfma_scatter<<<4096, 256, 0, stream>>>(ea, srcI, dstI, A, B, ee_w1, ee_b1,
                                                W3b + (size_t)l * H * H, c3 + l * H, agg, NE);
    node_update_kernel<<<1024, 512, 0, stream>>>(h, agg, Wn, Wn + 128 * H, nb, NN);
  }

  decoder_kernel<<<1024, 512, 0, stream>>>(h, d_w1, d_b1, d_w2, d_b2, d_w3, d_b3,
                                           bcd, bcr, (float*)d_out, NN);
}